// Round 8
// baseline (85.494 us; speedup 1.0000x reference)
//
#include <hip/hip_runtime.h>
#include <math.h>

#define T_SAVE 17

typedef float vf2 __attribute__((ext_vector_type(2)));
__device__ __forceinline__ vf2 vfma(vf2 a, vf2 b, vf2 c) {
    return __builtin_elementwise_fma(a, b, c);
}

// State (T, E, V): T' = -beta*V*T; E' = beta*V*T - delta*E; V' = p*E - c*V.
// Rate constants pre-multiplied by substep dt. Wall model (R2-R7): lone wave,
// wall = serial inst stream x ~6 cyc/inst (+ ~4us launch); minimize stream.
//
// Substep ladder 3/2/2 (end-time <=12.5 / <=21.5 / else). Stability over the
// param box (beta 1.5-2.5, delta .8-1.2, p 5-7, c 2.5-3.5), all eigs real neg:
//  - growth: |l-|<=6.7 -> z=2.23, |R|=0.44 (damps); l+ dt=0.87 -> 1.9e-3/step.
//  - days 13-21: active trajectories have l+<=0.75 -> |l-|<=5.45 -> z=2.73
//    (<2.78), |R|=0.92 marginal damping.
//  - tail: T depleted; eigs -> -delta,-c; z<=1.75. NSUB=1 would be z=3.5,
//    |R|=2.7 DIVERGENT -> 2 is the floor.
// absmax plateau 0.125 unchanged from NSUB=64 down through 5/3/2 -> budget
// (thr 0.49) nearly unspent; this round spends some.

__device__ __forceinline__ void stepS(float& T, float& E, float& V,
                                      float B, float Dl, float P, float C)
{
    float w1 = B * V,  a1 = Dl * E,  r1 = C * V;
    float m1 = w1 * T;
    float e1 = fmaf(w1, T, -a1);
    float v1 = fmaf(P, E, -r1);
    float Tb = fmaf(-0.5f, m1, T), Eb = fmaf(0.5f, e1, E), Vb = fmaf(0.5f, v1, V);

    float w2 = B * Vb, a2 = Dl * Eb, r2 = C * Vb;
    float m2 = w2 * Tb;
    float e2 = fmaf(w2, Tb, -a2);
    float v2 = fmaf(P, Eb, -r2);
    float Tc = fmaf(-0.5f, m2, T), Ec = fmaf(0.5f, e2, E), Vc = fmaf(0.5f, v2, V);

    float w3 = B * Vc, a3 = Dl * Ec, r3 = C * Vc;
    float m3 = w3 * Tc;
    float e3 = fmaf(w3, Tc, -a3);
    float v3 = fmaf(P, Ec, -r3);
    float Td = T - m3, Ed = E + e3, Vd = V + v3;

    float w4 = B * Vd, a4 = Dl * Ed, r4 = C * Vd;
    float m4 = w4 * Td;
    float e4 = fmaf(w4, Td, -a4);
    float v4 = fmaf(P, Ed, -r4);

    const float s = 1.0f / 6.0f;
    T = fmaf(-s, fmaf(2.0f, m2 + m3, m1 + m4), T);
    E = fmaf( s, fmaf(2.0f, e2 + e3, e1 + e4), E);
    V = fmaf( s, fmaf(2.0f, v2 + v3, v1 + v4), V);
}

__device__ __forceinline__ void stepP(vf2& T, vf2& E, vf2& V,
                                      vf2 B, vf2 Dl, vf2 P, vf2 C)
{
    vf2 w1 = B * V,  a1 = Dl * E,  r1 = C * V;
    vf2 m1 = w1 * T;
    vf2 e1 = vfma(w1, T, -a1);
    vf2 v1 = vfma(P, E, -r1);
    vf2 Tb = vfma((vf2)(-0.5f), m1, T), Eb = vfma((vf2)0.5f, e1, E), Vb = vfma((vf2)0.5f, v1, V);

    vf2 w2 = B * Vb, a2 = Dl * Eb, r2 = C * Vb;
    vf2 m2 = w2 * Tb;
    vf2 e2 = vfma(w2, Tb, -a2);
    vf2 v2 = vfma(P, Eb, -r2);
    vf2 Tc = vfma((vf2)(-0.5f), m2, T), Ec = vfma((vf2)0.5f, e2, E), Vc = vfma((vf2)0.5f, v2, V);

    vf2 w3 = B * Vc, a3 = Dl * Ec, r3 = C * Vc;
    vf2 m3 = w3 * Tc;
    vf2 e3 = vfma(w3, Tc, -a3);
    vf2 v3 = vfma(P, Ec, -r3);
    vf2 Td = T - m3, Ed = E + e3, Vd = V + v3;

    vf2 w4 = B * Vd, a4 = Dl * Ed, r4 = C * Vd;
    vf2 m4 = w4 * Td;
    vf2 e4 = vfma(w4, Td, -a4);
    vf2 v4 = vfma(P, Ed, -r4);

    const vf2 s = (vf2)(1.0f / 6.0f);
    T = vfma(-s, vfma((vf2)2.0f, m2 + m3, m1 + m4), T);
    E = vfma( s, vfma((vf2)2.0f, e2 + e3, e1 + e4), E);
    V = vfma( s, vfma((vf2)2.0f, v2 + v3, v1 + v4), V);
}

// ---- General-path helpers (fallback, conservative ladder 6/4/3) ----
__device__ __forceinline__ int nsub_for(float tend) {
    return tend <= 12.5f ? 6 : (tend <= 21.5f ? 4 : 3);
}

__device__ __forceinline__ void seg_s(float& T, float& E, float& V,
                                      float dt_seg, int nsub,
                                      float beta, float delta, float p, float c)
{
    float dt = dt_seg * (nsub == 6 ? (1.0f / 6.0f) : nsub == 4 ? 0.25f
                       : nsub == 3 ? (1.0f / 3.0f) : 1.0f / (float)nsub);
    float B = beta * dt, Dl = delta * dt, P = p * dt, C = c * dt;
    if (nsub == 6) {
        #pragma unroll
        for (int s = 0; s < 6; ++s) stepS(T, E, V, B, Dl, P, C);
    } else if (nsub == 4) {
        #pragma unroll
        for (int s = 0; s < 4; ++s) stepS(T, E, V, B, Dl, P, C);
    } else if (nsub == 3) {
        #pragma unroll
        for (int s = 0; s < 3; ++s) stepS(T, E, V, B, Dl, P, C);
    } else {
        for (int s = 0; s < nsub; ++s) stepS(T, E, V, B, Dl, P, C);
    }
}

__device__ __forceinline__ void seg_p(vf2& T, vf2& E, vf2& V,
                                      vf2 dt_seg, int nsub,
                                      float beta, float delta, float p, float c)
{
    vf2 dt = dt_seg * (nsub == 6 ? (1.0f / 6.0f) : nsub == 4 ? 0.25f
                     : nsub == 3 ? (1.0f / 3.0f) : 1.0f / (float)nsub);
    vf2 B = (vf2)beta * dt, Dl = (vf2)delta * dt, P = (vf2)p * dt, C = (vf2)c * dt;
    if (nsub == 6) {
        #pragma unroll
        for (int s = 0; s < 6; ++s) stepP(T, E, V, B, Dl, P, C);
    } else if (nsub == 4) {
        #pragma unroll
        for (int s = 0; s < 4; ++s) stepP(T, E, V, B, Dl, P, C);
    } else if (nsub == 3) {
        #pragma unroll
        for (int s = 0; s < 3; ++s) stepP(T, E, V, B, Dl, P, C);
    } else {
        for (int s = 0; s < nsub; ++s) stepP(T, E, V, B, Dl, P, C);
    }
}

__global__ __launch_bounds__(64, 1)
void Simulate_22497038696790_kernel(
    const float* __restrict__ days1, const float* __restrict__ days2,
    const float* __restrict__ D0,    const float* __restrict__ E0,
    const float* __restrict__ V01,   const float* __restrict__ V02,
    const float* __restrict__ beta_, const float* __restrict__ delta_,
    const float* __restrict__ p_,    const float* __restrict__ c_,
    const int*   __restrict__ treatment_,
    float* __restrict__ out, int nb)
{
    int b = blockIdx.x * blockDim.x + threadIdx.x;
    if (b >= nb) return;

    const int treatment = *treatment_;
    const float beta  = beta_[b];
    const float delta = delta_[b];
    const float p     = p_[b];
    const float c     = c_[b];

    float E1 = E0[b];
    float T1 = 1.0f - D0[b] - E1;
    float V1 = treatment ? V01[b] : 0.0f;

    auto save1 = [&](int t, float T, float E, float V) {
        size_t base = (size_t)t * nb + b;
        out[(size_t)(0 * T_SAVE) * nb + base] = 1.0f - T - E;  // D
        out[(size_t)(1 * T_SAVE) * nb + base] = E;
        out[(size_t)(2 * T_SAVE) * nb + base] = V;
        out[(size_t)(3 * T_SAVE) * nb + base] = __logf(V);
    };
    auto save2 = [&](int t, float T, float E, float V) {
        size_t base = (size_t)t * nb + b;
        out[(size_t)(4 * T_SAVE) * nb + base] = 1.0f - T - E;  // D
        out[(size_t)(5 * T_SAVE) * nb + base] = E;
        out[(size_t)(6 * T_SAVE) * nb + base] = V;
        out[(size_t)(7 * T_SAVE) * nb + base] = __logf(V);
    };

    // ---- Runtime check: do the time grids match setup_inputs()? ----
    // days1 = 5..21 step 1 (t0=5), days2 = 15..31 step 1 (t0=15). Uniform
    // branch; if it fails, fall through to the fully general path below.
    bool ok = true;
    #pragma unroll
    for (int t = 0; t < T_SAVE; ++t) {
        ok = ok && (days1[t] == 5.0f + (float)t) && (days2[t] == 15.0f + (float)t);
    }

    if (ok) {
        // ======== FAST PATH: static schedule, dt=1 segments, idx=10 ========
        const float i3 = 1.0f / 3.0f, i2 = 0.5f;
        const float B3 = beta * i3, Dl3 = delta * i3, P3 = p * i3, C3 = c * i3;
        const float B2 = beta * i2, Dl2 = delta * i2, P2 = p * i2, C2 = c * i2;

        save1(0, T1, E1, V1);                        // day 5: zero-dt segment
        for (int t = 1; t <= 7; ++t) {               // days 6..12: NSUB=3
            #pragma unroll
            for (int s = 0; s < 3; ++s) stepS(T1, E1, V1, B3, Dl3, P3, C3);
            save1(t, T1, E1, V1);
        }
        for (int t = 8; t <= 10; ++t) {              // days 13..15: NSUB=2
            #pragma unroll
            for (int s = 0; s < 2; ++s) stepS(T1, E1, V1, B2, Dl2, P2, C2);
            save1(t, T1, E1, V1);
        }
        // Phase-2 init from day-15 state (idx=10); days2[0]=15 is zero-dt.
        float V2i = treatment ? V1 + V02[b] : V1;
        save2(0, T1, E1, V2i);

        // days 16..21: phase-1 tail + phase-2 head packed 2-wide, NSUB=2
        vf2 T = {T1, T1}, E = {E1, E1}, V = {V1, V2i};
        vf2 B2p = (vf2)B2, Dl2p = (vf2)Dl2, P2p = (vf2)P2, C2p = (vf2)C2;
        for (int t = 11; t <= 16; ++t) {
            #pragma unroll
            for (int s = 0; s < 2; ++s) stepP(T, E, V, B2p, Dl2p, P2p, C2p);
            save1(t, T.x, E.x, V.x);
            save2(t - 10, T.y, E.y, V.y);
        }
        float T2 = T.y, E2 = E.y, V2 = V.y;
        for (int t = 7; t <= 16; ++t) {              // days 22..31: NSUB=2
            #pragma unroll
            for (int s = 0; s < 2; ++s) stepS(T2, E2, V2, B2, Dl2, P2, C2);
            save2(t, T2, E2, V2);
        }
        return;
    }

    // ======== GENERAL PATH (conservative ladder 6/4/3) ========
    int idx = 0;
    for (int t = 0; t < T_SAVE; ++t) {
        if (days1[t] == 15.0f) { idx = t; break; }
    }

    float tprev1 = 5.0f;
    int t1 = 0;
    for (; t1 <= idx; ++t1) {
        float tn = days1[t1];
        float dts = tn - tprev1;
        if (dts != 0.0f)
            seg_s(T1, E1, V1, dts, nsub_for(tn), beta, delta, p, c);
        tprev1 = tn;
        save1(t1, T1, E1, V1);
    }

    float T2c = T1, E2c = E1, V2c = V1;
    if (treatment) V2c += V02[b];
    float tprev2 = 15.0f;
    int t2 = 0;
    for (; t2 < T_SAVE; ++t2) {
        float tn = days2[t2];
        if (tn != tprev2) break;
        save2(t2, T2c, E2c, V2c);
    }

    for (; t1 < T_SAVE && t2 < T_SAVE; ++t1, ++t2) {
        float tn1 = days1[t1];
        float dts1 = tn1 - tprev1;
        float tn2 = days2[t2];
        float dts2 = tn2 - tprev2;
        int n1 = nsub_for(tn1), n2 = nsub_for(tn2);
        if (dts1 != 0.0f && dts2 != 0.0f && n1 == n2) {
            vf2 T = {T1, T2c}, E = {E1, E2c}, V = {V1, V2c};
            vf2 dts = {dts1, dts2};
            seg_p(T, E, V, dts, n1, beta, delta, p, c);
            T1 = T.x; E1 = E.x; V1 = V.x;
            T2c = T.y; E2c = E.y; V2c = V.y;
        } else {
            if (dts1 != 0.0f) seg_s(T1, E1, V1, dts1, n1, beta, delta, p, c);
            if (dts2 != 0.0f) seg_s(T2c, E2c, V2c, dts2, n2, beta, delta, p, c);
        }
        tprev1 = tn1;
        tprev2 = tn2;
        save1(t1, T1, E1, V1);
        save2(t2, T2c, E2c, V2c);
    }

    for (; t1 < T_SAVE; ++t1) {
        float tn = days1[t1];
        float dts = tn - tprev1;
        if (dts != 0.0f)
            seg_s(T1, E1, V1, dts, nsub_for(tn), beta, delta, p, c);
        tprev1 = tn;
        save1(t1, T1, E1, V1);
    }
    for (; t2 < T_SAVE; ++t2) {
        float tn = days2[t2];
        float dts = tn - tprev2;
        if (dts != 0.0f)
            seg_s(T2c, E2c, V2c, dts, nsub_for(tn), beta, delta, p, c);
        tprev2 = tn;
        save2(t2, T2c, E2c, V2c);
    }
}

extern "C" void kernel_launch(void* const* d_in, const int* in_sizes, int n_in,
                              void* d_out, int out_size, void* d_ws, size_t ws_size,
                              hipStream_t stream)
{
    const float* days1 = (const float*)d_in[0];
    const float* days2 = (const float*)d_in[1];
    const float* D0    = (const float*)d_in[2];
    const float* E0    = (const float*)d_in[3];
    const float* V01   = (const float*)d_in[4];
    const float* V02   = (const float*)d_in[5];
    const float* beta  = (const float*)d_in[6];
    const float* delta = (const float*)d_in[7];
    const float* p     = (const float*)d_in[8];
    const float* c     = (const float*)d_in[9];
    const int*   trt   = (const int*)d_in[10];
    float* out = (float*)d_out;

    int nb = in_sizes[2];                 // batch size from D0
    int block = 64;                       // 1 wave/block; 256 blocks ~ 1 per CU
    int grid = (nb + block - 1) / block;
    Simulate_22497038696790_kernel<<<grid, block, 0, stream>>>(
        days1, days2, D0, E0, V01, V02, beta, delta, p, c, trt, out, nb);
}